// Round 16
// baseline (26.430 us; speedup 1.0000x reference)
//
#include <hip/hip_runtime.h>
#include <cstdint>
#include <cstddef>

typedef _Float16 half8 __attribute__((ext_vector_type(8)));
typedef float f32x4  __attribute__((ext_vector_type(4)));
typedef float f32x16 __attribute__((ext_vector_type(16)));

static constexpr int kN = 256;               // state dim (N == K)
static constexpr size_t kHalfB = 64 * 1024;  // one ks-half of packed B
static constexpr size_t kLDS   = kHalfB;     // 64 KiB -> 2 blocks/CU

// Pack A_stacked[t] (fp32 [n][k]) into f16 32x32x16 B-fragment order,
// ks-half major. Unit u = (ksh, nt, kst): a16[(u*64 + l)*8 + j] =
//   A[nt*32 + (l&31)][ksh*128 + kst*16 + (l>>5)*8 + j]
__global__ __launch_bounds__(256) void hippo_prep(
    const float* __restrict__ A_stacked, const int* __restrict__ tptr,
    _Float16* __restrict__ a16)
{
    const int t = tptr[0];
    const float* __restrict__ A = A_stacked + (size_t)t * kN * kN;
    const int tid = blockIdx.x * 256 + threadIdx.x;   // 0..8191
    const int u   = tid >> 6;        // 0..127
    const int l   = tid & 63;
    const int ksh = u >> 6;          // 0..1
    const int nt  = (u >> 3) & 7;    // 0..7 (32-col tile)
    const int kst = u & 7;           // 0..7 (16-k step)
    const int row = nt * 32 + (l & 31);
    const int k0  = ksh * 128 + kst * 16 + ((l >> 5) << 3);
    const float* __restrict__ src = A + (size_t)row * kN + k0;
    f32x4 v0 = *(const f32x4*)(src);
    f32x4 v1 = *(const f32x4*)(src + 4);
    half8 h;
    h[0] = (_Float16)v0[0]; h[1] = (_Float16)v0[1];
    h[2] = (_Float16)v0[2]; h[3] = (_Float16)v0[3];
    h[4] = (_Float16)v1[0]; h[5] = (_Float16)v1[1];
    h[6] = (_Float16)v1[2]; h[7] = (_Float16)v1[3];
    ((half8*)a16)[tid] = h;
}

// out[m][n] = sum_k c[m][k] * A_t[n][k] + b[n] * f[m]
// 32x32x16 MFMA. 256-thr blocks (4 waves = 2m x 2n), 64 rows/block, grid 512,
// ks-half LDS staging (64 KiB, parity-staggered) -> 2 blocks/CU.
// Each wave: 32 rows x 128 cols (4 n-tiles of 32) -> LDS bytes/row HALVED
// vs 16x16 (same 1 KB B-frag feeds 4x output). acc = 4 x f32x16 = 64 VGPR.
__global__ __launch_bounds__(256, 2) void hippo_gemm(
    const float* __restrict__ c, const float* __restrict__ f,
    const float* __restrict__ Bst, const int* __restrict__ tptr,
    const _Float16* __restrict__ a16, float* __restrict__ out)
{
    extern __shared__ char lds_raw[];

    const int tid  = threadIdx.x;
    const int l    = tid & 63;
    const int wid  = tid >> 6;        // 0..3
    const int wm   = wid & 1;         // m-half (32 rows)
    const int wn   = wid >> 1;        // n-half (128 cols)
    const int lo32 = l & 31;
    const int hi2  = l >> 5;          // 0..1
    const int bid  = blockIdx.x;
    const int m0   = bid * 64 + wm * 32;
    const int ntb  = wn * 4;          // first global 32-col tile
    const int hA   = bid & 1;         // parity-staggered first ks-half
    const int hB   = hA ^ 1;

    // ---- DMA half hA into LDS ----
    const char* __restrict__ gsrcA = (const char*)a16 + (size_t)hA * kHalfB;
    #pragma unroll
    for (int i = 0; i < 16; ++i) {
        const size_t off = (size_t)(i * 4 + wid) * 1024 + (size_t)l * 16;
        __builtin_amdgcn_global_load_lds(
            (const __attribute__((address_space(1))) void*)(gsrcA + off),
            (__attribute__((address_space(3))) void*)(lds_raw + off),
            16, 0, 0);
    }

    // ---- c loads half hA: lane -> row m0+lo32, k = hA*128 + kst*16 + hi2*8 ----
    const float* __restrict__ cptr = c + (size_t)(m0 + lo32) * kN + (hi2 << 3);
    f32x4 cv0[8], cv1[8];
    #pragma unroll
    for (int kst = 0; kst < 8; ++kst) {
        cv0[kst] = *(const f32x4*)(cptr + hA * 128 + kst * 16);
        cv1[kst] = *(const f32x4*)(cptr + hA * 128 + kst * 16 + 4);
    }

    // ---- bias loads ----
    const int t = tptr[0];
    const float* __restrict__ brow = Bst + (size_t)t * kN + wn * 128;
    float bvs[4];
    #pragma unroll
    for (int nt = 0; nt < 4; ++nt) bvs[nt] = brow[nt * 32 + lo32];
    float fv[16];
    const float* __restrict__ fbase = f + m0 + (hi2 << 2);
    #pragma unroll
    for (int r = 0; r < 16; ++r) fv[r] = fbase[(r & 3) + ((r >> 2) << 3)];

    __syncthreads();   // drains DMA(hA) + c(hA)

    // ---- cvt af (cv dies) ----
    half8 af[8];
    #pragma unroll
    for (int kst = 0; kst < 8; ++kst) {
        af[kst][0] = (_Float16)cv0[kst][0]; af[kst][1] = (_Float16)cv0[kst][1];
        af[kst][2] = (_Float16)cv0[kst][2]; af[kst][3] = (_Float16)cv0[kst][3];
        af[kst][4] = (_Float16)cv1[kst][0]; af[kst][5] = (_Float16)cv1[kst][1];
        af[kst][6] = (_Float16)cv1[kst][2]; af[kst][7] = (_Float16)cv1[kst][3];
    }

    // ---- issue c loads half hB (hide under compute hA) ----
    f32x4 dv0[8], dv1[8];
    #pragma unroll
    for (int kst = 0; kst < 8; ++kst) {
        dv0[kst] = *(const f32x4*)(cptr + hB * 128 + kst * 16);
        dv1[kst] = *(const f32x4*)(cptr + hB * 128 + kst * 16 + 4);
    }

    // ---- compute half hA: kst-outer, 4 independent acc chains ----
    const half8* __restrict__ Bs = (const half8*)lds_raw;
    f32x16 acc[4];
    #pragma unroll
    for (int i = 0; i < 4; ++i)
        #pragma unroll
        for (int r = 0; r < 16; ++r) acc[i][r] = 0.f;
    #pragma unroll
    for (int kst = 0; kst < 8; ++kst) {
        #pragma unroll
        for (int nt = 0; nt < 4; ++nt) {
            half8 bf = Bs[((ntb + nt) * 8 + kst) * 64 + l];
            acc[nt] = __builtin_amdgcn_mfma_f32_32x32x16_f16(af[kst], bf, acc[nt], 0, 0, 0);
        }
    }

    __syncthreads();   // LDS reads of half hA complete -> safe to overwrite

    // ---- DMA half hB; cvt ag under its latency ----
    const char* __restrict__ gsrcB = (const char*)a16 + (size_t)hB * kHalfB;
    #pragma unroll
    for (int i = 0; i < 16; ++i) {
        const size_t off = (size_t)(i * 4 + wid) * 1024 + (size_t)l * 16;
        __builtin_amdgcn_global_load_lds(
            (const __attribute__((address_space(1))) void*)(gsrcB + off),
            (__attribute__((address_space(3))) void*)(lds_raw + off),
            16, 0, 0);
    }
    half8 ag[8];
    #pragma unroll
    for (int kst = 0; kst < 8; ++kst) {
        ag[kst][0] = (_Float16)dv0[kst][0]; ag[kst][1] = (_Float16)dv0[kst][1];
        ag[kst][2] = (_Float16)dv0[kst][2]; ag[kst][3] = (_Float16)dv0[kst][3];
        ag[kst][4] = (_Float16)dv1[kst][0]; ag[kst][5] = (_Float16)dv1[kst][1];
        ag[kst][6] = (_Float16)dv1[kst][2]; ag[kst][7] = (_Float16)dv1[kst][3];
    }

    __syncthreads();   // drains DMA(hB)

    // ---- compute half hB per nt-pair (2 chains) + streamed stores ----
    // C/D: col = l&31, row = (r&3) + 8*(r>>2) + 4*hi2
    float* __restrict__ obase = out + (size_t)(m0 + (hi2 << 2)) * kN + wn * 128 + lo32;
    #pragma unroll
    for (int np = 0; np < 4; np += 2) {
        #pragma unroll
        for (int kst = 0; kst < 8; ++kst) {
            half8 bf0 = Bs[((ntb + np) * 8 + kst) * 64 + l];
            half8 bf1 = Bs[((ntb + np + 1) * 8 + kst) * 64 + l];
            acc[np]     = __builtin_amdgcn_mfma_f32_32x32x16_f16(ag[kst], bf0, acc[np], 0, 0, 0);
            acc[np + 1] = __builtin_amdgcn_mfma_f32_32x32x16_f16(ag[kst], bf1, acc[np + 1], 0, 0, 0);
        }
        #pragma unroll
        for (int r = 0; r < 16; ++r) {
            const int row_off = (r & 3) + ((r >> 2) << 3);
            obase[(size_t)row_off * kN + np * 32]       = acc[np][r]     + bvs[np] * fv[r];
            obase[(size_t)row_off * kN + (np + 1) * 32] = acc[np + 1][r] + bvs[np + 1] * fv[r];
        }
    }
}

extern "C" void kernel_launch(void* const* d_in, const int* in_sizes, int n_in,
                              void* d_out, int out_size, void* d_ws, size_t ws_size,
                              hipStream_t stream) {
    const float* c   = (const float*)d_in[0];
    const float* f   = (const float*)d_in[1];
    const float* A   = (const float*)d_in[2];
    const float* B   = (const float*)d_in[3];
    const int*   t   = (const int*)d_in[4];
    float* out = (float*)d_out;
    _Float16* a16 = (_Float16*)d_ws;   // 128 KiB packed A[t] f16, ks-half-major

    const int batch = in_sizes[0] / kN;   // 32768

    hipFuncSetAttribute((const void*)hippo_gemm,
                        hipFuncAttributeMaxDynamicSharedMemorySize,
                        (int)kLDS);

    hipLaunchKernelGGL(hippo_prep, dim3(32), dim3(256), 0, stream, A, t, a16);
    hipLaunchKernelGGL(hippo_gemm, dim3(batch / 64), dim3(256), kLDS, stream,
                       c, f, B, t, a16, out);
}